// Round 5
// baseline (244.557 us; speedup 1.0000x reference)
//
#include <hip/hip_runtime.h>

#define NSEQ   16
#define KVH    8
#define NG     4      // query heads per kv head
#define HD     128
#define BS     16
#define MAXB   256
#define PART   256    // tokens per block (4 waves x 64)
#define NPART  16
#define WPT    64     // tokens per wave
#define PSTRIDE 520   // floats per partition record: o[512], l[4], m, pad
#define SCALE_F 0.08838834764831845f

// Kernel 1: per (seq, kv_head, partition). Four independent waves, each owning
// a 64-token slice. Deep-pipelined: 32 outstanding K loads, then 32 outstanding
// V loads issued BEFORE the softmax so the memory pipe never drains.
// Q lives in LDS so its reads use lgkmcnt and never FIFO-drain the vmcnt bursts.
// __launch_bounds__(256,3): cap ~170 VGPR so the allocator keeps the bursts live.
__global__ __launch_bounds__(256, 3) void pa_partial_kernel(
    const float* __restrict__ query,
    const float* __restrict__ key,
    const float* __restrict__ value,
    const float* __restrict__ key_cache,
    const float* __restrict__ value_cache,
    const int*   __restrict__ block_tables,
    const int*   __restrict__ context_lens,
    float*       __restrict__ ws)
{
    const int bid = blockIdx.x;
    const int p   = bid & (NPART - 1);
    const int kvh = (bid >> 4) & (KVH - 1);
    const int s   = bid >> 7;

    const int ctx = context_lens[s];
    const int t0  = p * PART;
    if (t0 >= ctx) return;

    __shared__ float q_lds[NG * HD];      // 2 KB, shared by all 4 waves
    __shared__ float p_lds[4][NG][WPT];   // 4 KB per-wave probabilities
    __shared__ float o_lds[4][NG * HD];   // 8 KB per-wave partial outputs
    __shared__ float ml_lds[4][8];        // per-wave m, l[4]

    const int tid  = threadIdx.x;
    const int wv   = tid >> 6;
    const int lane = tid & 63;
    const int tw0  = t0 + wv * WPT;
    const bool wact = (tw0 < ctx);

    // ---- stage Q into LDS (one copy per block; keeps vmcnt clean later) ----
    const float* qsrc = query + ((size_t)s * KVH + kvh) * (NG * HD);
    ((float2*)q_lds)[tid] = ((const float2*)qsrc)[tid];
    __syncthreads();

    float m_w = -1e30f;
    float l_w[NG] = {0.f, 0.f, 0.f, 0.f};

    if (wact) {
        // ---- QK: one token per lane, 32-deep load burst ----
        const int t  = tw0 + lane;                     // < 4096 always: in-bounds
        const int bt = block_tables[s * MAXB + (t >> 4)];
        const float* kb = key_cache + (size_t)bt * (KVH * HD * BS)
                                    + (size_t)kvh * (HD * BS) + (t & 15) * 8;

        float4 kr[32];
        #pragma unroll
        for (int j = 0; j < 16; ++j) {
            kr[2 * j]     = *(const float4*)(kb + j * 128);
            kr[2 * j + 1] = *(const float4*)(kb + j * 128 + 4);
        }

        float sc[NG] = {0.f, 0.f, 0.f, 0.f};
        #pragma unroll
        for (int j = 0; j < 16; ++j) {
            const float4 ka = kr[2 * j];
            const float4 kc = kr[2 * j + 1];
            #pragma unroll
            for (int g = 0; g < NG; ++g) {
                const float4 qa = *(const float4*)(&q_lds[g * HD + j * 8]);
                const float4 qb = *(const float4*)(&q_lds[g * HD + j * 8 + 4]);
                sc[g] += qa.x * ka.x + qa.y * ka.y + qa.z * ka.z + qa.w * ka.w
                       + qb.x * kc.x + qb.y * kc.y + qb.z * kc.z + qb.w * kc.w;
            }
        }

        // new-token K correction: token ctx-1's key comes from the `key` input
        if (t == ctx - 1) {
            const float4* kn4 = (const float4*)(key + ((size_t)s * KVH + kvh) * HD);
            float ns[NG] = {0.f, 0.f, 0.f, 0.f};
            #pragma unroll
            for (int c = 0; c < 32; ++c) {
                const float4 k4 = kn4[c];
                #pragma unroll
                for (int g = 0; g < NG; ++g) {
                    ns[g] += q_lds[g * HD + c * 4 + 0] * k4.x + q_lds[g * HD + c * 4 + 1] * k4.y
                           + q_lds[g * HD + c * 4 + 2] * k4.z + q_lds[g * HD + c * 4 + 3] * k4.w;
                }
            }
            #pragma unroll
            for (int g = 0; g < NG; ++g) sc[g] = ns[g];
        }

        // ---- issue V bursts NOW (independent of softmax): 32 outstanding ----
        int btv[4];
        #pragma unroll
        for (int b = 0; b < 4; ++b)
            btv[b] = block_tables[s * MAXB + (tw0 >> 4) + b];  // uniform, in-bounds

        float4 vr0[16], vr1[16];
        #pragma unroll
        for (int b = 0; b < 4; ++b) {
            const float* vb0 = value_cache + (size_t)btv[b] * (KVH * HD * BS)
                                           + (size_t)kvh * (HD * BS) + lane * BS;
            const float* vb1 = vb0 + 64 * BS;
            #pragma unroll
            for (int c = 0; c < 4; ++c) {
                vr0[b * 4 + c] = *(const float4*)(vb0 + c * 4);
                vr1[b * 4 + c] = *(const float4*)(vb1 + c * 4);
            }
        }

        // ---- softmax (VALU only; V loads in flight underneath) ----
        float mv;
        if (t < ctx) {
            #pragma unroll
            for (int g = 0; g < NG; ++g) sc[g] *= SCALE_F;
            mv = fmaxf(fmaxf(sc[0], sc[1]), fmaxf(sc[2], sc[3]));
        } else {
            #pragma unroll
            for (int g = 0; g < NG; ++g) sc[g] = -1e30f;
            mv = -1e30f;
        }
        #pragma unroll
        for (int o = 32; o; o >>= 1) mv = fmaxf(mv, __shfl_xor(mv, o));
        m_w = mv;

        float pr[NG];
        #pragma unroll
        for (int g = 0; g < NG; ++g) {
            pr[g] = __expf(sc[g] - m_w);      // exactly 0 for masked tokens
            p_lds[wv][g][lane] = pr[g];
            l_w[g] = pr[g];
        }
        #pragma unroll
        for (int o = 32; o; o >>= 1) {
            l_w[0] += __shfl_xor(l_w[0], o);
            l_w[1] += __shfl_xor(l_w[1], o);
            l_w[2] += __shfl_xor(l_w[2], o);
            l_w[3] += __shfl_xor(l_w[3], o);
        }

        if (lane == 0) {
            ml_lds[wv][0] = m_w;
            #pragma unroll
            for (int g = 0; g < NG; ++g) ml_lds[wv][1 + g] = l_w[g];
        }

        // ---- PV from registers (p via LDS broadcast, conflict-free) ----
        float a0[NG] = {0.f, 0.f, 0.f, 0.f};
        float a1[NG] = {0.f, 0.f, 0.f, 0.f};
        const float4* pl4 = (const float4*)&p_lds[wv][0][0];
        #pragma unroll
        for (int b = 0; b < 4; ++b) {
            #pragma unroll
            for (int c = 0; c < 4; ++c) {
                const float4 v0 = vr0[b * 4 + c];
                const float4 v1 = vr1[b * 4 + c];
                #pragma unroll
                for (int g = 0; g < NG; ++g) {
                    const float4 pg = pl4[g * 16 + b * 4 + c];
                    a0[g] += pg.x * v0.x + pg.y * v0.y + pg.z * v0.z + pg.w * v0.w;
                    a1[g] += pg.x * v1.x + pg.y * v1.y + pg.z * v1.z + pg.w * v1.w;
                }
            }
        }

        // new-token V correction: replace stale cache V at token ctx-1
        const int tl = ctx - 1 - tw0;
        if (tl >= 0 && tl < WPT) {
            const int btn = block_tables[s * MAXB + ((ctx - 1) >> 4)];
            const float* vbase = value_cache + (size_t)btn * (KVH * HD * BS)
                                             + (size_t)kvh * (HD * BS) + ((ctx - 1) & 15);
            const float dv0 = value[((size_t)s * KVH + kvh) * HD + lane]      - vbase[lane * BS];
            const float dv1 = value[((size_t)s * KVH + kvh) * HD + lane + 64] - vbase[(lane + 64) * BS];
            #pragma unroll
            for (int g = 0; g < NG; ++g) {
                const float pt = p_lds[wv][g][tl];
                a0[g] += pt * dv0;
                a1[g] += pt * dv1;
            }
        }

        #pragma unroll
        for (int g = 0; g < NG; ++g) {
            o_lds[wv][g * HD + lane]      = a0[g];
            o_lds[wv][g * HD + 64 + lane] = a1[g];
        }
    } else {
        if (lane == 0) {
            ml_lds[wv][0] = -1e30f;
            #pragma unroll
            for (int g = 0; g < NG; ++g) ml_lds[wv][1 + g] = 0.f;
        }
        #pragma unroll
        for (int i = 0; i < 8; ++i) o_lds[wv][i * 64 + lane] = 0.f;
    }

    __syncthreads();   // single merge barrier

    const float m0 = ml_lds[0][0], m1 = ml_lds[1][0], m2 = ml_lds[2][0], m3 = ml_lds[3][0];
    const float M  = fmaxf(fmaxf(m0, m1), fmaxf(m2, m3));
    const float w0 = __expf(m0 - M), w1 = __expf(m1 - M);
    const float w2 = __expf(m2 - M), w3 = __expf(m3 - M);

    float* rec = ws + (size_t)bid * PSTRIDE;
    #pragma unroll
    for (int r = 0; r < 2; ++r) {
        const int idx = tid + r * 256;
        rec[idx] = w0 * o_lds[0][idx] + w1 * o_lds[1][idx]
                 + w2 * o_lds[2][idx] + w3 * o_lds[3][idx];
    }
    if (tid < NG) {
        rec[512 + tid] = w0 * ml_lds[0][1 + tid] + w1 * ml_lds[1][1 + tid]
                       + w2 * ml_lds[2][1 + tid] + w3 * ml_lds[3][1 + tid];
    }
    if (tid == 4) rec[516] = M;
}

// Kernel 2: LSE-combine partitions -> output. One (seq, kvh, g) per block.
__global__ __launch_bounds__(128) void pa_reduce_kernel(
    const float* __restrict__ ws,
    const int*   __restrict__ context_lens,
    float*       __restrict__ out)
{
    const int b    = blockIdx.x;        // ((s*KVH)+kvh)*NG + g
    const int g    = b & 3;
    const int pair = b >> 2;            // s*KVH + kvh
    const int s    = pair >> 3;
    const int kvh  = pair & 7;
    const int ctx  = context_lens[s];
    const int np   = (ctx + PART - 1) / PART;

    const int d = threadIdx.x;
    const float* base = ws + (size_t)pair * NPART * PSTRIDE;

    float M = -1e30f;
    for (int p2 = 0; p2 < np; ++p2) M = fmaxf(M, base[p2 * PSTRIDE + 516]);

    float L = 0.f, acc = 0.f;
    for (int p2 = 0; p2 < np; ++p2) {
        const float* rec = base + p2 * PSTRIDE;
        const float w = __expf(rec[516] - M);
        L   += w * rec[512 + g];
        acc += w * rec[g * HD + d];
    }

    out[(size_t)s * (KVH * NG * HD) + (size_t)(kvh * NG + g) * HD + d] = acc / L;
}

extern "C" void kernel_launch(void* const* d_in, const int* in_sizes, int n_in,
                              void* d_out, int out_size, void* d_ws, size_t ws_size,
                              hipStream_t stream) {
    const float* query       = (const float*)d_in[0];
    const float* key         = (const float*)d_in[1];
    const float* value       = (const float*)d_in[2];
    const float* key_cache   = (const float*)d_in[3];
    const float* value_cache = (const float*)d_in[4];
    const int*   block_tables  = (const int*)d_in[5];
    const int*   context_lens  = (const int*)d_in[6];
    // d_in[7] slot_mapping unused: slot is derivable from context_lens + block_tables

    float* out = (float*)d_out;
    float* ws  = (float*)d_ws;   // needs 16*8*16*520*4 = 4.26 MB

    pa_partial_kernel<<<NSEQ * KVH * NPART, 256, 0, stream>>>(
        query, key, value, key_cache, value_cache, block_tables, context_lens, ws);
    pa_reduce_kernel<<<NSEQ * KVH * NG, 128, 0, stream>>>(ws, context_lens, out);
}

// Round 7
// 85.021 us; speedup vs baseline: 2.8764x; 2.8764x over previous
//
#include <hip/hip_runtime.h>

#define NSEQ   16
#define KVH    8
#define NG     4      // query heads per kv head
#define HD     128
#define BS     16
#define MAXB   256
#define PART   256    // tokens per work item (4 waves x 64)
#define NPART  16
#define NITEMS (NSEQ * KVH * NPART)   // 2048 work items
#define WPT    64     // tokens per wave
#define PSTRIDE 520   // floats per partition record: o[512], l[4], m, pad
#define REC_BYTES ((size_t)NITEMS * PSTRIDE * 4)
#define SCALE_F 0.08838834764831845f
#define NWORKERS 1024

// Kernel 1: persistent worker blocks steal (seq, kv_head, partition) items from
// a global atomic counter for CU load balance. Grab protocol is TWO barriers:
//   B1: tid0's item_s write is visible to all; then everyone reads item_s;
//   B2: everyone has read; only after B2 may any path loop and overwrite item_s.
// This keeps the barrier sequence block-uniform on every path (the round-6 bug:
// the inactive-`continue` path let tid0 overwrite item_s with no barrier, and
// s_barrier matches by arrival count, so waves desynchronized across DIFFERENT
// __syncthreads call sites -> corrupted records).
__global__ __launch_bounds__(256) void pa_partial_kernel(
    const float* __restrict__ query,
    const float* __restrict__ key,
    const float* __restrict__ value,
    const float* __restrict__ key_cache,
    const float* __restrict__ value_cache,
    const int*   __restrict__ block_tables,
    const int*   __restrict__ context_lens,
    float*       __restrict__ ws,
    unsigned int* __restrict__ counter)
{
    __shared__ float p_lds[4][NG][WPT];   // per-wave probabilities
    __shared__ float o_lds[4][NG * HD];   // per-wave partial outputs
    __shared__ float ml_lds[4][8];        // per-wave m, l[4]
    __shared__ int   item_s;

    const int tid  = threadIdx.x;
    const int wv   = tid >> 6;
    const int lane = tid & 63;

    for (;;) {
        if (tid == 0) item_s = (int)atomicAdd(counter, 1u);
        __syncthreads();                  // B1: item_s write visible
        const int item = item_s;
        __syncthreads();                  // B2: all threads have read item_s;
                                          // safe for any later overwrite
        if (item >= NITEMS) return;

        const int p   = item & (NPART - 1);
        const int kvh = (item >> 4) & (KVH - 1);
        const int s   = item >> 7;
        const int ctx = context_lens[s];
        const int t0  = p * PART;
        if (t0 >= ctx) continue;          // inactive item: barrier-safe skip

        const int tw0  = t0 + wv * WPT;
        const bool wact = (tw0 < ctx);

        const float* q = query + ((size_t)s * KVH + kvh) * (NG * HD);

        float m_w = -1e30f;
        float l_w[NG] = {0.f, 0.f, 0.f, 0.f};

        if (wact) {
            // ---- QK: one token per lane ----
            const int t  = tw0 + lane;                     // < 4096: in-bounds
            const int bt = block_tables[s * MAXB + (t >> 4)];
            const float* kb = key_cache + (size_t)bt * (KVH * HD * BS)
                                        + (size_t)kvh * (HD * BS) + (t & 15) * 8;

            float sc[NG] = {0.f, 0.f, 0.f, 0.f};
            #pragma unroll
            for (int j = 0; j < 16; ++j) {
                const float4 ka = *(const float4*)(kb + j * 128);
                const float4 kc = *(const float4*)(kb + j * 128 + 4);
                #pragma unroll
                for (int g = 0; g < NG; ++g) {
                    sc[g] += q[g * HD + j * 8 + 0] * ka.x + q[g * HD + j * 8 + 1] * ka.y
                           + q[g * HD + j * 8 + 2] * ka.z + q[g * HD + j * 8 + 3] * ka.w
                           + q[g * HD + j * 8 + 4] * kc.x + q[g * HD + j * 8 + 5] * kc.y
                           + q[g * HD + j * 8 + 6] * kc.z + q[g * HD + j * 8 + 7] * kc.w;
                }
            }

            // new-token K correction: token ctx-1's key comes from the `key` input
            if (t == ctx - 1) {
                const float4* kn4 = (const float4*)(key + ((size_t)s * KVH + kvh) * HD);
                float ns[NG] = {0.f, 0.f, 0.f, 0.f};
                #pragma unroll
                for (int c = 0; c < 32; ++c) {
                    const float4 k4 = kn4[c];
                    #pragma unroll
                    for (int g = 0; g < NG; ++g) {
                        ns[g] += q[g * HD + c * 4 + 0] * k4.x + q[g * HD + c * 4 + 1] * k4.y
                               + q[g * HD + c * 4 + 2] * k4.z + q[g * HD + c * 4 + 3] * k4.w;
                    }
                }
                #pragma unroll
                for (int g = 0; g < NG; ++g) sc[g] = ns[g];
            }

            float mv;
            if (t < ctx) {
                #pragma unroll
                for (int g = 0; g < NG; ++g) sc[g] *= SCALE_F;
                mv = fmaxf(fmaxf(sc[0], sc[1]), fmaxf(sc[2], sc[3]));
            } else {
                #pragma unroll
                for (int g = 0; g < NG; ++g) sc[g] = -1e30f;
                mv = -1e30f;
            }

            #pragma unroll
            for (int o = 32; o; o >>= 1) mv = fmaxf(mv, __shfl_xor(mv, o));
            m_w = mv;

            float pr[NG];
            #pragma unroll
            for (int g = 0; g < NG; ++g) {
                pr[g] = __expf(sc[g] - m_w);
                p_lds[wv][g][lane] = pr[g];
                l_w[g] = pr[g];
            }
            #pragma unroll
            for (int o = 32; o; o >>= 1) {
                l_w[0] += __shfl_xor(l_w[0], o);
                l_w[1] += __shfl_xor(l_w[1], o);
                l_w[2] += __shfl_xor(l_w[2], o);
                l_w[3] += __shfl_xor(l_w[3], o);
            }
        }

        if (lane == 0) {
            ml_lds[wv][0] = m_w;
            #pragma unroll
            for (int g = 0; g < NG; ++g) ml_lds[wv][1 + g] = l_w[g];
        }

        // ---- PV: wave-local, lane = d (two halves) ----
        if (wact) {
            const int nbv = min(4, (ctx - tw0 + 15) >> 4);
            int btv[4];
            #pragma unroll
            for (int b = 0; b < 4; ++b)
                btv[b] = block_tables[s * MAXB + (tw0 >> 4) + b];  // uniform, in-bounds

            const int tl = ctx - 1 - tw0;
            const float4* pl4 = (const float4*)&p_lds[wv][0][0];

            #pragma unroll 2
            for (int half = 0; half < 2; ++half) {
                const int d = lane + half * 64;
                float a[NG] = {0.f, 0.f, 0.f, 0.f};
                for (int b = 0; b < nbv; ++b) {
                    const float* vb = value_cache + (size_t)btv[b] * (KVH * HD * BS)
                                                  + (size_t)kvh * (HD * BS) + d * BS;
                    #pragma unroll
                    for (int c = 0; c < 4; ++c) {
                        const float4 v4 = *(const float4*)(vb + c * 4);
                        #pragma unroll
                        for (int g = 0; g < NG; ++g) {
                            const float4 pg = pl4[g * 16 + b * 4 + c];
                            a[g] += pg.x * v4.x + pg.y * v4.y + pg.z * v4.z + pg.w * v4.w;
                        }
                    }
                }
                if (tl >= 0 && tl < WPT) {
                    const int btn = block_tables[s * MAXB + ((ctx - 1) >> 4)];
                    const float vold = value_cache[(size_t)btn * (KVH * HD * BS)
                                                   + (size_t)kvh * (HD * BS) + d * BS + ((ctx - 1) & 15)];
                    const float vnew = value[((size_t)s * KVH + kvh) * HD + d];
                    const float dv = vnew - vold;
                    #pragma unroll
                    for (int g = 0; g < NG; ++g) a[g] += p_lds[wv][g][tl] * dv;
                }
                #pragma unroll
                for (int g = 0; g < NG; ++g) o_lds[wv][g * HD + d] = a[g];
            }
        } else {
            #pragma unroll
            for (int i = 0; i < 8; ++i) o_lds[wv][i * 64 + lane] = 0.f;
        }

        __syncthreads();   // merge the 4 wave records

        const float m0 = ml_lds[0][0], m1 = ml_lds[1][0], m2 = ml_lds[2][0], m3 = ml_lds[3][0];
        const float M  = fmaxf(fmaxf(m0, m1), fmaxf(m2, m3));
        const float w0 = __expf(m0 - M), w1 = __expf(m1 - M);
        const float w2 = __expf(m2 - M), w3 = __expf(m3 - M);

        float* rec = ws + (size_t)item * PSTRIDE;
        #pragma unroll
        for (int r = 0; r < 2; ++r) {
            const int idx = tid + r * 256;
            rec[idx] = w0 * o_lds[0][idx] + w1 * o_lds[1][idx]
                     + w2 * o_lds[2][idx] + w3 * o_lds[3][idx];
        }
        if (tid < NG) {
            rec[512 + tid] = w0 * ml_lds[0][1 + tid] + w1 * ml_lds[1][1 + tid]
                           + w2 * ml_lds[2][1 + tid] + w3 * ml_lds[3][1 + tid];
        }
        if (tid == 4) rec[516] = M;
        // next grab's B1 separates this item's o_lds reads from the next item's writes
    }
}

// Kernel 2: LSE-combine partitions -> output. One (seq, kvh, g) per block.
__global__ __launch_bounds__(128) void pa_reduce_kernel(
    const float* __restrict__ ws,
    const int*   __restrict__ context_lens,
    float*       __restrict__ out)
{
    const int b    = blockIdx.x;        // ((s*KVH)+kvh)*NG + g
    const int g    = b & 3;
    const int pair = b >> 2;            // s*KVH + kvh
    const int s    = pair >> 3;
    const int kvh  = pair & 7;
    const int ctx  = context_lens[s];
    const int np   = (ctx + PART - 1) / PART;

    const int d = threadIdx.x;
    const float* base = ws + (size_t)pair * NPART * PSTRIDE;

    float M = -1e30f;
    for (int p2 = 0; p2 < np; ++p2) M = fmaxf(M, base[p2 * PSTRIDE + 516]);

    float L = 0.f, acc = 0.f;
    for (int p2 = 0; p2 < np; ++p2) {
        const float* rec = base + p2 * PSTRIDE;
        const float w = __expf(rec[516] - M);
        L   += w * rec[512 + g];
        acc += w * rec[g * HD + d];
    }

    out[(size_t)s * (KVH * NG * HD) + (size_t)(kvh * NG + g) * HD + d] = acc / L;
}

extern "C" void kernel_launch(void* const* d_in, const int* in_sizes, int n_in,
                              void* d_out, int out_size, void* d_ws, size_t ws_size,
                              hipStream_t stream) {
    const float* query       = (const float*)d_in[0];
    const float* key         = (const float*)d_in[1];
    const float* value       = (const float*)d_in[2];
    const float* key_cache   = (const float*)d_in[3];
    const float* value_cache = (const float*)d_in[4];
    const int*   block_tables  = (const int*)d_in[5];
    const int*   context_lens  = (const int*)d_in[6];
    // d_in[7] slot_mapping unused: slot is derivable from context_lens + block_tables

    float* out = (float*)d_out;
    float* ws  = (float*)d_ws;   // records: 2048*520*4 = 4.26 MB, + 4 B counter
    unsigned int* counter = (unsigned int*)((char*)d_ws + REC_BYTES);

    hipMemsetAsync(counter, 0, sizeof(unsigned int), stream);
    pa_partial_kernel<<<NWORKERS, 256, 0, stream>>>(
        query, key, value, key_cache, value_cache, block_tables, context_lens, ws, counter);
    pa_reduce_kernel<<<NSEQ * KVH * NG, 128, 0, stream>>>(ws, context_lens, out);
}